// Round 11
// baseline (184.368 us; speedup 1.0000x reference)
//
#include <hip/hip_runtime.h>
#include <stdint.h>

// MultiHeadAttention: B=4, C=1024, NH=16, D=64, W=1500 (H=1)
// R11: GEMM core -> 256x128 tile, 8 waves (4M x 2N, wave 64x64), BK=32, 2-phase
// per K-tile with B-frags-in-regs, region-scheduled staging (A(t+1)->other buf at
// p0, B(t+2)->dead B region at p1), counted vmcnt(1) once per K-tile, setprio
// around MFMA clusters. 48KB LDS. qkv unified grid 572 blocks; gemm_out 188.
// Attn v5 / prep unchanged (R10-validated).

typedef unsigned short u16;
typedef __bf16 bf16x8 __attribute__((ext_vector_type(8)));
typedef float  f32x4  __attribute__((ext_vector_type(4)));
typedef unsigned int __attribute__((address_space(1))) as1_uint;
typedef unsigned int __attribute__((address_space(3))) as3_uint;

__device__ __forceinline__ u16 f2bf(float f) {            // RNE float->bf16
    unsigned u = __float_as_uint(f);
    u += 0x7fffu + ((u >> 16) & 1u);
    return (u16)(u >> 16);
}

__device__ __forceinline__ f32x4 fzero4() { f32x4 z = {0.f, 0.f, 0.f, 0.f}; return z; }

// async global->LDS, 16B per lane. LDS dest must be wave-uniform base + lane*16.
__device__ __forceinline__ void gld16(void* lds, const void* g) {
    __builtin_amdgcn_global_load_lds((const as1_uint*)g, (as3_uint*)lds, 16, 0, 0);
}

// key permutation within 32-groups: key [kappa(b4)|g(b3:2)|r(b1:0)] -> stored [g(b4:3)|kappa(b2)|r(b1:0)]
__device__ __forceinline__ int permw(int w) {
    return (w & ~31) | ((w & 12) << 1) | ((w & 16) >> 2) | (w & 3);
}

// ---------------- prep: weight cvt + x transpose + Vt pad-zero, one dispatch ----------------
__global__ void prep_k(const float* __restrict__ wq, const float* __restrict__ wk,
                       const float* __restrict__ wv, const float* __restrict__ wo,
                       u16* __restrict__ wb, const float* __restrict__ x,
                       u16* __restrict__ xb, u16* __restrict__ Vt) {
    __shared__ float tile[64][65];
    const int bid = blockIdx.x;
    if (bid < 4096) {                                   // weights fp32->bf16
        unsigned idx = bid * 256u + threadIdx.x;
        unsigned m = idx >> 18, r = idx & 0x3ffffu;
        const float* s = (m == 0) ? wq : (m == 1) ? wk : (m == 2) ? wv : wo;
        float4 v = ((const float4*)s)[r];
        uint2 o;
        o.x = (unsigned)f2bf(v.x) | ((unsigned)f2bf(v.y) << 16);
        o.y = (unsigned)f2bf(v.z) | ((unsigned)f2bf(v.w) << 16);
        ((uint2*)(wb + (m << 20)))[r] = o;
    } else if (bid < 5632) {                            // x [b][c][w] -> xb [b*w][c] bf16
        int bid2 = bid - 4096;
        const int xw = bid2 % 24, yc = (bid2 / 24) & 15, b = bid2 / 384;
        const int w0 = xw * 64, c0 = yc * 64;
        const int tw = threadIdx.x & 63, t4 = threadIdx.x >> 6;
#pragma unroll
        for (int i = 0; i < 16; i++) {
            int c = i * 4 + t4, w = w0 + tw;
            tile[c][tw] = (w < 1500) ? x[((b << 10) + c0 + c) * 1500 + w] : 0.f;
        }
        __syncthreads();
#pragma unroll
        for (int i = 0; i < 16; i++) {
            int wl = i * 4 + t4, w = w0 + wl;
            if (w < 1500) xb[((b * 1500 + w) << 10) + c0 + tw] = f2bf(tile[tw][wl]);
        }
    } else {                                            // zero Vt pad cols 1500..1503 (4096 rows)
        const int t = threadIdx.x;
        uint2 z; z.x = 0u; z.y = 0u;
#pragma unroll
        for (int i = 0; i < 16; i++) {
            int idx = i * 256 + t;                      // (b<<10)+o in [0,4096)
            *(uint2*)(Vt + (long)idx * 1504 + 1500) = z;
        }
    }
}

// ---------------- GEMM core v3: 256x128 tile, BK=32, 8 waves, 2-phase pipeline ----------------
// LDS 48KB: A bufs [2][256][32]bf16 @0 (b*16384), B bufs [2][128][32]bf16 @32768 (b*8192).
// 512 thr = 8 waves: wm = wv>>1 (M quarter, 64 rows), wn = wv&1 (N half, 64 cols).
// Swizzle (R9-validated): stage seg' = seg ^ ((row>>1)&3); read seg = (lg ^ ((row>>1)&3)).
__device__ __forceinline__ void stageAu(const u16* __restrict__ A, int arow0, int amax,
                                        int k0, unsigned char* abuf, int u) {
    const int t = threadIdx.x;
    int row = u * 128 + (t >> 2), seg = t & 3;
    int sseg = seg ^ ((row >> 1) & 3);
    int ar = arow0 + row; if (ar > amax) ar = amax;
    gld16(abuf + u * 8192 + (t << 4), A + ((long)ar << 10) + k0 + sseg * 8);
}
__device__ __forceinline__ void stageB1(const u16* __restrict__ Bm, int brow0, int bmax,
                                        int k0, unsigned char* bbuf) {
    const int t = threadIdx.x;
    int row = t >> 2, seg = t & 3;
    int sseg = seg ^ ((row >> 1) & 3);
    int br = brow0 + row; if (br > bmax) br = bmax;
    gld16(bbuf + (t << 4), Bm + ((long)br << 10) + k0 + sseg * 8);
}

// Pipeline invariants (issue-order analysis):
//   stages for K-tile v: B(v) @ (v-2).p1 ; A0,A1(v) @ (v-1).p0.
//   At v top: outstanding = [A01(v)=2, B(v+1)=1] -> vmcnt(1) lands A01(v) + all older.
//   Region deadness: B of buf b dead after v.p0 (frags in regs, reads complete pre-barrier);
//   A of buf b^1 dead since tile v-1 end. All stages target dead regions at issue time.
__device__ __forceinline__ void gemm_core25(const u16* __restrict__ A, int arow0, int amax,
                                            const u16* __restrict__ Bm, int brow0, int bmax,
                                            f32x4 (&acc)[4][4], unsigned char* lds) {
    const int t = threadIdx.x, l15 = t & 15, lg = (t >> 4) & 3;
    const int wv = t >> 6, wm = wv >> 1, wn = wv & 1;
#pragma unroll
    for (int im = 0; im < 4; im++)
#pragma unroll
        for (int in = 0; in < 4; in++) acc[im][in] = fzero4();

    unsigned char* A0 = lds;             // [2][256][32]
    unsigned char* B0 = lds + 32768;     // [2][128][32]

    // prologue: B(0), A0(0), A1(0), B(1)  -> 4 outstanding
    stageB1(Bm, brow0, bmax, 0, B0);
    stageAu(A, arow0, amax, 0, A0, 0);
    stageAu(A, arow0, amax, 0, A0, 1);
    stageB1(Bm, brow0, bmax, 32, B0 + 8192);

    for (int kt = 0; kt < 32; kt++) {
        const int b = kt & 1;
        if (kt < 31) asm volatile("s_waitcnt vmcnt(1)" ::: "memory");
        else         asm volatile("s_waitcnt vmcnt(0)" ::: "memory");
        __builtin_amdgcn_s_barrier();          // all waves' tile-kt data visible
        const unsigned char* Ab = A0 + (b << 14);
        const unsigned char* Bb = B0 + (b << 13);

        // ---- phase 0: B frags (held across tile) + A im0-1 ----
        bf16x8 bf[4], af0, af1;
#pragma unroll
        for (int in = 0; in < 4; in++) {
            int row = wn * 64 + in * 16 + l15;
            bf[in] = *(const bf16x8*)(Bb + (row << 6) + ((lg ^ ((row >> 1) & 3)) << 4));
        }
        {
            int r0 = wm * 64 + l15;
            af0 = *(const bf16x8*)(Ab + (r0 << 6) + ((lg ^ ((r0 >> 1) & 3)) << 4));
            int r1 = wm * 64 + 16 + l15;
            af1 = *(const bf16x8*)(Ab + (r1 << 6) + ((lg ^ ((r1 >> 1) & 3)) << 4));
        }
        if (kt < 31) {                          // stage A(kt+1) -> other buf (dead since kt-1)
            int nk0 = (kt + 1) << 5;
            stageAu(A, arow0, amax, nk0, A0 + ((b ^ 1) << 14), 0);
            stageAu(A, arow0, amax, nk0, A0 + ((b ^ 1) << 14), 1);
        }
        __builtin_amdgcn_s_setprio(1);
#pragma unroll
        for (int in = 0; in < 4; in++) {
            acc[0][in] = __builtin_amdgcn_mfma_f32_16x16x32_bf16(af0, bf[in], acc[0][in], 0, 0, 0);
            acc[1][in] = __builtin_amdgcn_mfma_f32_16x16x32_bf16(af1, bf[in], acc[1][in], 0, 0, 0);
        }
        __builtin_amdgcn_s_setprio(0);
        __builtin_amdgcn_s_barrier();           // B region of buf b now dead

        // ---- phase 1: A im2-3; stage B(kt+2) into dead B region ----
        bf16x8 af2, af3;
        {
            int r2 = wm * 64 + 32 + l15;
            af2 = *(const bf16x8*)(Ab + (r2 << 6) + ((lg ^ ((r2 >> 1) & 3)) << 4));
            int r3 = wm * 64 + 48 + l15;
            af3 = *(const bf16x8*)(Ab + (r3 << 6) + ((lg ^ ((r3 >> 1) & 3)) << 4));
        }
        if (kt < 30) stageB1(Bm, brow0, bmax, (kt + 2) << 5, B0 + (b << 13));
        __builtin_amdgcn_s_setprio(1);
#pragma unroll
        for (int in = 0; in < 4; in++) {
            acc[2][in] = __builtin_amdgcn_mfma_f32_16x16x32_bf16(af2, bf[in], acc[2][in], 0, 0, 0);
            acc[3][in] = __builtin_amdgcn_mfma_f32_16x16x32_bf16(af3, bf[in], acc[3][in], 0, 0, 0);
        }
        __builtin_amdgcn_s_setprio(0);
        __builtin_amdgcn_s_barrier();           // A of buf b dead for stage at (kt+1).p0
    }
}

// ---------------- fused Q,K,V projections (unified grid, 572 blocks) ----------------
// bid<384: QK, M=tokens(6000, 24 tiles x 256), N=channels(2048 = wq||wk, 16 tiles x 128).
// bid>=384: V, M=channels(1024, 4 x 256), N=tokens(6000, 47 x 128) -> Vt permuted.
__global__ __launch_bounds__(512) void qkv_k(const u16* __restrict__ xb, const u16* __restrict__ wb,
                                             const float* __restrict__ bq, const float* __restrict__ bv,
                                             u16* __restrict__ Q, u16* __restrict__ K,
                                             u16* __restrict__ Vt) {
    __shared__ __attribute__((aligned(16))) unsigned char lds[49152];
    const int p = blockIdx.x;
    // m204 bijective XCD swizzle, nwg=572: q=71, r=4
    const int xcd = p & 7, idx = p >> 3;
    const int bid = (xcd < 4 ? xcd * 72 : 288 + (xcd - 4) * 71) + idx;
    const int t = threadIdx.x, l15 = t & 15, lg = (t >> 4) & 3;
    const int wv = t >> 6, wm = wv >> 1, wn = wv & 1;
    f32x4 acc[4][4];

    if (bid < 384) {
        const int xt = bid % 24, yt = bid / 24;        // xt fast: share weight panel
        gemm_core25(xb, xt * 256, 5999, wb, yt * 128, 2047, acc, lds);
        const int m0 = xt * 256 + wm * 64, n0 = yt * 128 + wn * 64;
        const int z = yt >> 3;                          // 0: Q, 1: K
        u16* dst = z ? K : Q;
        const float qs = z ? 1.f : 0.18033688011112042f;   // SC folded into Q
#pragma unroll
        for (int im = 0; im < 4; im++) {
#pragma unroll
            for (int r = 0; r < 4; r++) {
                int tok = m0 + im * 16 + lg * 4 + r;
                if (tok < 6000) {
                    int b = tok / 1500, w = tok - b * 1500;
#pragma unroll
                    for (int in = 0; in < 4; in++) {
                        int o = (n0 + in * 16 + l15) & 1023;
                        float v = (acc[im][in][r] + (z ? 0.f : bq[o])) * qs;
                        dst[((((b << 4) + (o >> 6)) * 1500 + w) << 6) + (o & 63)] = f2bf(v);
                    }
                }
            }
        }
    } else {
        const int rem = bid - 384;                     // [0,188): 4 xt x 47 nt
        const int xt = rem & 3, nt = rem >> 2;         // xt fast: token panel shared
        gemm_core25(wb + (2u << 20), xt * 256, 1023, xb, nt * 128, 5999, acc, lds);
        const int m0 = xt * 256 + wm * 64, n0 = nt * 128 + wn * 64;
#pragma unroll
        for (int im = 0; im < 4; im++) {
#pragma unroll
            for (int r = 0; r < 4; r++) {
                int o = m0 + im * 16 + lg * 4 + r;
                float bi = bv[o];
#pragma unroll
                for (int in = 0; in < 4; in++) {
                    int tok = n0 + in * 16 + l15;
                    if (tok < 6000) {
                        int b = tok / 1500, w = tok - b * 1500;
                        Vt[((b << 10) + o) * 1504 + permw(w)] = f2bf(acc[im][in][r] + bi);
                    }
                }
            }
        }
    }
}

// ---------------- output projection: M=channels(1024, 4x256), N=tokens(6000, 47x128) ----------------
__global__ __launch_bounds__(512) void gemm_out_k(const u16* __restrict__ Ow, const u16* __restrict__ wb,
                                                  const float* __restrict__ bo, float* __restrict__ out) {
    __shared__ __attribute__((aligned(16))) unsigned char lds[49152];
    const int p = blockIdx.x;
    // m204 bijective XCD swizzle, nwg=188: q=23, r=4
    const int xcd = p & 7, idx = p >> 3;
    const int lb = (xcd < 4 ? xcd * 24 : 96 + (xcd - 4) * 23) + idx;
    const int xt = lb & 3, nt = lb >> 2;
    const int t = threadIdx.x, l15 = t & 15, lg = (t >> 4) & 3;
    const int wv = t >> 6, wm = wv >> 1, wn = wv & 1;
    f32x4 acc[4][4];
    gemm_core25(wb + (3u << 20), xt * 256, 1023, Ow, nt * 128, 5999, acc, lds);
    const int m0 = xt * 256 + wm * 64, n0 = nt * 128 + wn * 64;
#pragma unroll
    for (int im = 0; im < 4; im++) {
#pragma unroll
        for (int r = 0; r < 4; r++) {
            int o = m0 + im * 16 + lg * 4 + r;
            float bi = bo[o];
#pragma unroll
            for (int in = 0; in < 4; in++) {
                int tok = n0 + in * 16 + l15;
                if (tok < 6000) {
                    int b = tok / 1500, w = tok - b * 1500;
                    out[(long)((b << 10) + o) * 1500 + w] = acc[im][in][r] + bi;
                }
            }
        }
    }
}

// ---------------- flash attention v5 (unchanged from R10) ----------------
__global__ __launch_bounds__(512) void attn_k(const u16* __restrict__ Q, const u16* __restrict__ K,
                                              const u16* __restrict__ Vt, u16* __restrict__ O) {
    __shared__ __attribute__((aligned(16))) unsigned char lds[32768];

    const int p = blockIdx.x;
    const int lb = (p & 7) * 96 + (p >> 3);         // 768 = 8*96; bh-major per XCD (K/V L2 reuse)
    const int qt = lb % 12, bh = lb / 12;
    const int b = bh >> 4, h = bh & 15;
    const int t = threadIdx.x, wv = t >> 6, l15 = t & 15, g = (t >> 4) & 3;
    const int sk7 = l15 & 7;

    // Q fragments (B-operand): col q = l15, k(d) = 8g..+7 (+32)
    int q_a = qt * 128 + wv * 16 + l15; if (q_a > 1499) q_a = 1499;
    const u16* qrow = Q + (((long)bh * 1500 + q_a) << 6);
    bf16x8 qb0 = *(const bf16x8*)(qrow + (g << 3));
    bf16x8 qb1 = *(const bf16x8*)(qrow + 32 + (g << 3));

    const u16* Kbh = K + (((long)bh * 1500) << 6);
    const u16* Vtb = Vt + (long)((b << 10) + (h << 6)) * 1504;

    // staging: each thread 16B K + 16B V, LDS linear dest, pre-swizzled source chunk
    const int srow = t >> 3;                        // 0..63
    const int ssw  = ((t & 7) ^ (srow & 7)) << 3;   // element offset of 8-elem segment
    unsigned char* kdst = lds + (t << 4);
    unsigned char* vdst = lds + 16384 + (t << 4);

    // hoisted source pointers (advance by constants; clamps peeled to last stage)
    const u16* kp_src = Kbh + ((long)srow << 6) + ssw;
    const u16* vp_src = Vtb + (long)srow * 1504 + ssw;

    f32x4 o_acc[4];
#pragma unroll
    for (int nf = 0; nf < 4; nf++) o_acc[nf] = fzero4();
    float l_part = 0.f;

    // prologue: stage tile 0 into buf 0
    gld16(kdst, kp_src);
    gld16(vdst, vp_src);
    kp_src += 4096; vp_src += 64;                   // -> tile 1
    __syncthreads();

    for (int tile = 0; tile < 24; ++tile) {
        const int cur = tile & 1;
        if (tile < 22) {        // stage tile+1 (rows < 1472: clamp-free)
            gld16(kdst + ((cur ^ 1) << 13), kp_src);
            gld16(vdst + ((cur ^ 1) << 13), vp_src);
            kp_src += 4096; vp_src += 64;
        } else if (tile == 22) {   // stage tile 23 (rows 1472..1535: clamp)
            int kg = 1472 + srow; if (kg > 1499) kg = 1499;
            gld16(kdst + ((cur ^ 1) << 13), Kbh + ((long)kg << 6) + ssw);
            int vc = 1472 + ssw; if (vc > 1496) vc = 1496;
            gld16(vdst + ((cur ^ 1) << 13), Vtb + (long)srow * 1504 + vc);
        }
        const unsigned char* Kl = lds + (cur << 13);
        const unsigned char* Vl = lds + 16384 + (cur << 13);

        // S^T = K Q^T : s[kt][r] = log2-domain score(key = 16kt+4g+r, q = l15)
        f32x4 s[4];
        __builtin_amdgcn_s_setprio(1);
#pragma unroll
        for (int kt = 0; kt < 4; kt++) {
            const unsigned char* kp = Kl + ((kt * 16 + l15) << 7);
            bf16x8 ka0 = *(const bf16x8*)(kp + ((g ^ sk7) << 4));
            bf16x8 ka1 = *(const bf16x8*)(kp + (((g + 4) ^ sk7) << 4));
            f32x4 z = fzero4();
            z = __builtin_amdgcn_mfma_f32_16x16x32_bf16(ka0, qb0, z, 0, 0, 0);
            z = __builtin_amdgcn_mfma_f32_16x16x32_bf16(ka1, qb1, z, 0, 0, 0);
            s[kt] = z;
        }
        __builtin_amdgcn_s_setprio(0);
        if (tile == 23) {   // mask keys >= 1500 (kv0 = 1472, 28 valid)
#pragma unroll
            for (int kt = 0; kt < 4; kt++)
#pragma unroll
                for (int r = 0; r < 4; r++)
                    if (kt * 16 + g * 4 + r >= 28) s[kt][r] = -1e30f;
        }

        // P = exp2(s); shift-free (no max). psum in-lane.
        float pv[4][4];
        float psum = 0.f;
#pragma unroll
        for (int kt = 0; kt < 4; kt++) {
#pragma unroll
            for (int r = 0; r < 4; r++) {
                float p2 = exp2f(s[kt][r]);
                pv[kt][r] = p2;
                psum += p2;
            }
        }
        l_part += psum;   // lane-partial (this lane's 16 keys); cross-g reduce at end

        // PV A-frags: elem j of pa0 = P[key 16*(j>>2) + 4g + (j&3)] -- matches permuted V cols 8g+j
        bf16x8 pa0, pa1;
#pragma unroll
        for (int j = 0; j < 8; j++) {
            pa0[j] = (__bf16)pv[j >> 2][j & 3];
            pa1[j] = (__bf16)pv[2 + (j >> 2)][j & 3];
        }

        // O += P V : B = V_lds[d][stored cols 8g..+7 (+32)] swizzled
        __builtin_amdgcn_s_setprio(1);
#pragma unroll
        for (int nf = 0; nf < 4; nf++) {
            const unsigned char* vp = Vl + ((nf * 16 + l15) << 7);
            bf16x8 vb0 = *(const bf16x8*)(vp + ((g ^ sk7) << 4));
            bf16x8 vb1 = *(const bf16x8*)(vp + (((4 + g) ^ sk7) << 4));
            o_acc[nf] = __builtin_amdgcn_mfma_f32_16x16x32_bf16(pa0, vb0, o_acc[nf], 0, 0, 0);
            o_acc[nf] = __builtin_amdgcn_mfma_f32_16x16x32_bf16(pa1, vb1, o_acc[nf], 0, 0, 0);
        }
        __builtin_amdgcn_s_setprio(0);
        __syncthreads();   // next-tile loads landed; everyone done with buf[cur]
    }

    // epilogue: total l across g-groups, normalize, write O[token][c]
    l_part += __shfl_xor(l_part, 16);
    l_part += __shfl_xor(l_part, 32);
    float inv = 1.f / l_part;     // per query q = l15
#pragma unroll
    for (int r = 0; r < 4; r++) {
        float invr = __shfl(inv, g * 4 + r);      // for o_acc row q = 4g+r
        int q = qt * 128 + wv * 16 + g * 4 + r;
        if (q < 1500) {
            u16* dst = O + ((long)(b * 1500 + q) << 10) + (h << 6);
#pragma unroll
            for (int nf = 0; nf < 4; nf++)
                dst[nf * 16 + l15] = f2bf(o_acc[nf][r] * invr);
        }
    }
}

// ---------------- launch ----------------
extern "C" void kernel_launch(void* const* d_in, const int* in_sizes, int n_in,
                              void* d_out, int out_size, void* d_ws, size_t ws_size,
                              hipStream_t stream) {
    const float* x  = (const float*)d_in[0];
    const float* Wq = (const float*)d_in[1];
    const float* bq = (const float*)d_in[2];
    const float* Wk = (const float*)d_in[3];
    const float* Wv = (const float*)d_in[4];
    const float* bv = (const float*)d_in[5];
    const float* Wo = (const float*)d_in[6];
    const float* bo = (const float*)d_in[7];
    float* out = (float*)d_out;

    // workspace layout (bytes):
    //   xb [6000][1024] bf16 : 12,288,000   (reused as O_ws after qkv consumes it)
    //   wb [4][2^20]    bf16 :  8,388,608   (wq|wk|wv|wo rows = output channels)
    //   Q  [4][16][1500][64] : 12,288,000   (pre-scaled by 0.125*log2e)
    //   K                    : 12,288,000
    //   Vt [4][1024][1504]   : 12,320,768   (key-permuted cols, cols 1500-1503 zeroed)
    const size_t NEED = 57573376;
    if (ws_size < NEED) return;   // visible failure if workspace too small

    unsigned char* ws = (unsigned char*)d_ws;
    u16* xb = (u16*)(ws);
    u16* wb = (u16*)(ws + 12288000);
    u16* Qw = (u16*)(ws + 20676608);
    u16* Kw = (u16*)(ws + 32964608);
    u16* Vt = (u16*)(ws + 45252608);

    prep_k<<<dim3(5633), dim3(256), 0, stream>>>(Wq, Wk, Wv, Wo, wb, x, xb, Vt);
    qkv_k<<<dim3(572), dim3(512), 0, stream>>>(xb, wb, bq, bv, Qw, Kw, Vt);   // 384 QK + 188 V
    attn_k<<<dim3(768), dim3(512), 0, stream>>>(Qw, Kw, Vt, xb /* -> O_ws */);
    gemm_out_k<<<dim3(188), dim3(512), 0, stream>>>(xb, wb, bo, out);
}

// Round 12
// 178.750 us; speedup vs baseline: 1.0314x; 1.0314x over previous
//
#include <hip/hip_runtime.h>
#include <stdint.h>

// MultiHeadAttention: B=4, C=1024, NH=16, D=64, W=1500 (H=1)
// R12: GEMM core reverted verbatim to R10 (ring-3 counted-vmcnt; R11's phase-split
// regressed: 3 barriers/K-tile > gain). Attn v6: 4 waves x 2 query-sets (32 q/wave)
// -- each K/V LDS fragment read feeds 2 MFMAs, halving the binding LDS-read pipe
// (was 2.5x over MFMA at 8 waves x 1 set). Same grid/LDS/1-barrier structure.

typedef unsigned short u16;
typedef __bf16 bf16x8 __attribute__((ext_vector_type(8)));
typedef float  f32x4  __attribute__((ext_vector_type(4)));
typedef unsigned int __attribute__((address_space(1))) as1_uint;
typedef unsigned int __attribute__((address_space(3))) as3_uint;

__device__ __forceinline__ u16 f2bf(float f) {            // RNE float->bf16
    unsigned u = __float_as_uint(f);
    u += 0x7fffu + ((u >> 16) & 1u);
    return (u16)(u >> 16);
}

__device__ __forceinline__ f32x4 fzero4() { f32x4 z = {0.f, 0.f, 0.f, 0.f}; return z; }

// async global->LDS, 16B per lane. LDS dest must be wave-uniform base + lane*16.
__device__ __forceinline__ void gld16(void* lds, const void* g) {
    __builtin_amdgcn_global_load_lds((const as1_uint*)g, (as3_uint*)lds, 16, 0, 0);
}

// key permutation within 32-groups: key [kappa(b4)|g(b3:2)|r(b1:0)] -> stored [g(b4:3)|kappa(b2)|r(b1:0)]
__device__ __forceinline__ int permw(int w) {
    return (w & ~31) | ((w & 12) << 1) | ((w & 16) >> 2) | (w & 3);
}

// ---------------- prep: weight cvt + x transpose + Vt pad-zero, one dispatch ----------------
__global__ void prep_k(const float* __restrict__ wq, const float* __restrict__ wk,
                       const float* __restrict__ wv, const float* __restrict__ wo,
                       u16* __restrict__ wb, const float* __restrict__ x,
                       u16* __restrict__ xb, u16* __restrict__ Vt) {
    __shared__ float tile[64][65];
    const int bid = blockIdx.x;
    if (bid < 4096) {                                   // weights fp32->bf16
        unsigned idx = bid * 256u + threadIdx.x;
        unsigned m = idx >> 18, r = idx & 0x3ffffu;
        const float* s = (m == 0) ? wq : (m == 1) ? wk : (m == 2) ? wv : wo;
        float4 v = ((const float4*)s)[r];
        uint2 o;
        o.x = (unsigned)f2bf(v.x) | ((unsigned)f2bf(v.y) << 16);
        o.y = (unsigned)f2bf(v.z) | ((unsigned)f2bf(v.w) << 16);
        ((uint2*)(wb + (m << 20)))[r] = o;
    } else if (bid < 5632) {                            // x [b][c][w] -> xb [b*w][c] bf16
        int bid2 = bid - 4096;
        const int xw = bid2 % 24, yc = (bid2 / 24) & 15, b = bid2 / 384;
        const int w0 = xw * 64, c0 = yc * 64;
        const int tw = threadIdx.x & 63, t4 = threadIdx.x >> 6;
#pragma unroll
        for (int i = 0; i < 16; i++) {
            int c = i * 4 + t4, w = w0 + tw;
            tile[c][tw] = (w < 1500) ? x[((b << 10) + c0 + c) * 1500 + w] : 0.f;
        }
        __syncthreads();
#pragma unroll
        for (int i = 0; i < 16; i++) {
            int wl = i * 4 + t4, w = w0 + wl;
            if (w < 1500) xb[((b * 1500 + w) << 10) + c0 + tw] = f2bf(tile[tw][wl]);
        }
    } else {                                            // zero Vt pad cols 1500..1503 (4096 rows)
        const int t = threadIdx.x;
        uint2 z; z.x = 0u; z.y = 0u;
#pragma unroll
        for (int i = 0; i < 16; i++) {
            int idx = i * 256 + t;                      // (b<<10)+o in [0,4096)
            *(uint2*)(Vt + (long)idx * 1504 + 1500) = z;
        }
    }
}

// ---------------- GEMM core: 128x128 tile, BK=32, NT, XOR-swizzled LDS (R10 verbatim) ----------------
// 3-slot ring: A slots @0/8K/16K, B slots @24K/32K/40K (48KB). 256 thr = 4 waves (2Mx2N).
__device__ __forceinline__ void stage32(const u16* __restrict__ A, int arow0, int amax,
                                        const u16* __restrict__ Bm, int brow0, int bmax,
                                        int k0, unsigned char* lds, int slot) {
    const int t = threadIdx.x;
    unsigned char* ab = lds + slot * 8192;
    unsigned char* bb = lds + 24576 + slot * 8192;
#pragma unroll
    for (int i = 0; i < 2; i++) {
        int xo = (i * 256 + t) << 4;          // byte offset in 8KB buffer
        int row = xo >> 6, seg = (xo >> 4) & 3;
        int sseg = seg ^ ((row >> 1) & 3);    // pre-swizzled source segment
        int ar = arow0 + row; if (ar > amax) ar = amax;
        int br = brow0 + row; if (br > bmax) br = bmax;
        gld16(ab + xo, A  + ((long)ar << 10) + k0 + sseg * 8);
        gld16(bb + xo, Bm + ((long)br << 10) + k0 + sseg * 8);
    }
}

// T4 counted-vmcnt ring loop (R9-validated). Loads span 2 K-steps.
__device__ __forceinline__ void gemm_core128(const u16* __restrict__ A, int arow0, int amax,
                                             const u16* __restrict__ Bm, int brow0, int bmax,
                                             f32x4 (&acc)[4][4], unsigned char* lds) {
    const int t = threadIdx.x, l15 = t & 15, lg = (t >> 4) & 3;
    const int wv = t >> 6, wm = wv >> 1, wn = wv & 1;
#pragma unroll
    for (int im = 0; im < 4; im++)
#pragma unroll
        for (int in = 0; in < 4; in++) acc[im][in] = fzero4();

    stage32(A, arow0, amax, Bm, brow0, bmax, 0, lds, 0);
    stage32(A, arow0, amax, Bm, brow0, bmax, 32, lds, 1);

    int slot = 0;
    for (int kt = 0; kt < 32; kt++) {
        if (kt < 31) asm volatile("s_waitcnt vmcnt(4)" ::: "memory");
        else         asm volatile("s_waitcnt vmcnt(0)" ::: "memory");
        __builtin_amdgcn_s_barrier();
        if (kt < 30) {
            int ns = slot + 2; if (ns >= 3) ns -= 3;   // slot (kt+2) % 3
            stage32(A, arow0, amax, Bm, brow0, bmax, (kt + 2) << 5, lds, ns);
        }
        const unsigned char* ab = lds + slot * 8192;
        const unsigned char* bb = lds + 24576 + slot * 8192;
        bf16x8 af[4], bfr[4];
#pragma unroll
        for (int im = 0; im < 4; im++) {
            int row = wm * 64 + im * 16 + l15;
            af[im] = *(const bf16x8*)(ab + (row << 6) + ((lg ^ ((row >> 1) & 3)) << 4));
        }
#pragma unroll
        for (int in = 0; in < 4; in++) {
            int row = wn * 64 + in * 16 + l15;
            bfr[in] = *(const bf16x8*)(bb + (row << 6) + ((lg ^ ((row >> 1) & 3)) << 4));
        }
#pragma unroll
        for (int im = 0; im < 4; im++)
#pragma unroll
            for (int in = 0; in < 4; in++)
                acc[im][in] = __builtin_amdgcn_mfma_f32_16x16x32_bf16(af[im], bfr[in], acc[im][in], 0, 0, 0);
        slot = slot + 1; if (slot >= 3) slot = 0;
    }
}

// ---------------- fused Q,K,V projections (R10 verbatim) ----------------
__global__ __launch_bounds__(256, 3) void qkv_k(const u16* __restrict__ xb, const u16* __restrict__ wb,
                                                const float* __restrict__ bq, const float* __restrict__ bv,
                                                u16* __restrict__ Q, u16* __restrict__ K,
                                                u16* __restrict__ Vt) {
    __shared__ __attribute__((aligned(16))) unsigned char lds[49152];
    const int p = blockIdx.x;
    const int bid = (p & 7) * 142 + (p >> 3);          // 1136 = 8 * 142, bijective
    const int t = threadIdx.x, l15 = t & 15, lg = (t >> 4) & 3;
    const int wv = t >> 6, wm = wv >> 1, wn = wv & 1;
    f32x4 acc[4][4];

    if (bid < 752) {
        const int z = bid / 376, rem = bid % 376;
        const int xt = rem % 47, yt = rem / 47;        // xt fast: consecutive share B-panel
        gemm_core128(xb, xt * 128, 5999, wb + (z << 20), yt * 128, 1023, acc, lds);
        const int m0 = xt * 128 + wm * 64, n0 = yt * 128 + wn * 64;
        u16* dst = z ? K : Q;
        const float* bias = z ? nullptr : bq;
        const float qs = z ? 1.f : 0.18033688011112042f;   // SC folded into Q
#pragma unroll
        for (int im = 0; im < 4; im++) {
#pragma unroll
            for (int r = 0; r < 4; r++) {
                int tok = m0 + im * 16 + lg * 4 + r;
                if (tok < 6000) {
                    int b = tok / 1500, w = tok - b * 1500;
#pragma unroll
                    for (int in = 0; in < 4; in++) {
                        int o = n0 + in * 16 + l15;
                        float v = (acc[im][in][r] + (bias ? bias[o] : 0.f)) * qs;
                        dst[((((b << 4) + (o >> 6)) * 1500 + w) << 6) + (o & 63)] = f2bf(v);
                    }
                }
            }
        }
    } else {
        const int rem = bid - 752;                 // [0, 384): 8 xt x 12 yt x 4 b
        const int xt = rem & 7, rest = rem >> 3;
        const int yt = rest % 12, b = rest / 12;
        gemm_core128(wb + (2u << 20), xt * 128, 1023, xb + b * 1500 * 1024, yt * 128, 1499, acc, lds);
        const int m0 = xt * 128 + wm * 64, n0 = yt * 128 + wn * 64;
#pragma unroll
        for (int im = 0; im < 4; im++) {
#pragma unroll
            for (int r = 0; r < 4; r++) {
                int o = m0 + im * 16 + lg * 4 + r;
                float bi = bv[o];
#pragma unroll
                for (int in = 0; in < 4; in++) {
                    int w = n0 + in * 16 + l15;
                    if (w < 1500)
                        Vt[((b << 10) + o) * 1504 + permw(w)] = f2bf(acc[im][in][r] + bi);
                }
            }
        }
    }
}

// ---------------- output projection: M=channels(1024), N=all tokens(6000) (R10 verbatim) ----------------
__global__ __launch_bounds__(256, 3) void gemm_out_k(const u16* __restrict__ Ow, const u16* __restrict__ wb,
                                                     const float* __restrict__ bo, float* __restrict__ out) {
    __shared__ __attribute__((aligned(16))) unsigned char lds[49152];
    const int p = blockIdx.x;
    const int lb = (p & 7) * 47 + (p >> 3);            // 376 = 8 * 47, bijective
    const int xt = lb & 7, nt = lb >> 3;
    f32x4 acc[4][4];
    gemm_core128(wb + (3u << 20), xt * 128, 1023, Ow, nt * 128, 5999, acc, lds);
    const int t = threadIdx.x, l15 = t & 15, lg = (t >> 4) & 3;
    const int wv = t >> 6, wm = wv >> 1, wn = wv & 1;
    const int m0 = xt * 128 + wm * 64;
    const int n0 = nt * 128 + wn * 64;
#pragma unroll
    for (int im = 0; im < 4; im++) {
#pragma unroll
        for (int r = 0; r < 4; r++) {
            int o = m0 + im * 16 + lg * 4 + r;
            float bi = bo[o];
#pragma unroll
            for (int in = 0; in < 4; in++) {
                int tok = n0 + in * 16 + l15;
                if (tok < 6000) {
                    int b = tok / 1500, w = tok - b * 1500;
                    out[(long)((b << 10) + o) * 1500 + w] = acc[im][in][r] + bi;
                }
            }
        }
    }
}

// ---------------- flash attention v6: 4 waves x 2 query-sets (32 q/wave) ----------------
// Each K/V LDS fragment read feeds 2 MFMAs (one per q-set) -> LDS-read pipe halved.
// 256 thr, QBLK=128, grid 768 (bh-major XCD-chunked). Shift-free softmax (R10).
__global__ __launch_bounds__(256) void attn_k(const u16* __restrict__ Q, const u16* __restrict__ K,
                                              const u16* __restrict__ Vt, u16* __restrict__ O) {
    __shared__ __attribute__((aligned(16))) unsigned char lds[32768];

    const int p = blockIdx.x;
    const int lb = (p & 7) * 96 + (p >> 3);         // 768 = 8*96; bh-major per XCD (K/V L2 reuse)
    const int qt = lb % 12, bh = lb / 12;
    const int b = bh >> 4, h = bh & 15;
    const int t = threadIdx.x, wv = t >> 6, l15 = t & 15, g = (t >> 4) & 3;
    const int sk7 = l15 & 7;

    // Q fragments (B-operand) for 2 query sets: qA = base+l15, qB = base+16+l15
    int qA = qt * 128 + wv * 32 + l15;      if (qA > 1499) qA = 1499;
    int qB = qt * 128 + wv * 32 + 16 + l15; if (qB > 1499) qB = 1499;
    const u16* qrA = Q + (((long)bh * 1500 + qA) << 6);
    const u16* qrB = Q + (((long)bh * 1500 + qB) << 6);
    bf16x8 qb0A = *(const bf16x8*)(qrA + (g << 3));
    bf16x8 qb1A = *(const bf16x8*)(qrA + 32 + (g << 3));
    bf16x8 qb0B = *(const bf16x8*)(qrB + (g << 3));
    bf16x8 qb1B = *(const bf16x8*)(qrB + 32 + (g << 3));

    const u16* Kbh = K + (((long)bh * 1500) << 6);
    const u16* Vtb = Vt + (long)((b << 10) + (h << 6)) * 1504;

    // staging: 256 thr x 2 chunks x 16B for each of K,V; linear dest, pre-swizzled source
    const int i1 = t + 256;
    const int sr0 = t >> 3,  sw0 = ((t & 7) ^ (sr0 & 7)) << 3;
    const int sr1 = i1 >> 3, sw1 = ((i1 & 7) ^ (sr1 & 7)) << 3;
    unsigned char* kd0 = lds + (t << 4);
    unsigned char* kd1 = lds + (i1 << 4);
    unsigned char* vd0 = lds + 16384 + (t << 4);
    unsigned char* vd1 = lds + 16384 + (i1 << 4);
    const u16* kp0 = Kbh + ((long)sr0 << 6) + sw0;
    const u16* kp1 = Kbh + ((long)sr1 << 6) + sw1;
    const u16* vp0 = Vtb + (long)sr0 * 1504 + sw0;
    const u16* vp1 = Vtb + (long)sr1 * 1504 + sw1;

    f32x4 o_acc[2][4];
#pragma unroll
    for (int s2 = 0; s2 < 2; s2++)
#pragma unroll
        for (int nf = 0; nf < 4; nf++) o_acc[s2][nf] = fzero4();
    float lA = 0.f, lB = 0.f;

    // prologue: stage tile 0 into buf 0
    gld16(kd0, kp0); gld16(kd1, kp1);
    gld16(vd0, vp0); gld16(vd1, vp1);
    kp0 += 4096; kp1 += 4096; vp0 += 64; vp1 += 64;
    __syncthreads();

    for (int tile = 0; tile < 24; ++tile) {
        const int cur = tile & 1;
        if (tile < 22) {        // stage tile+1 (rows < 1472: clamp-free)
            gld16(kd0 + ((cur ^ 1) << 13), kp0);
            gld16(kd1 + ((cur ^ 1) << 13), kp1);
            gld16(vd0 + ((cur ^ 1) << 13), vp0);
            gld16(vd1 + ((cur ^ 1) << 13), vp1);
            kp0 += 4096; kp1 += 4096; vp0 += 64; vp1 += 64;
        } else if (tile == 22) {   // stage tile 23 (rows 1472..1535: clamp)
            int k0c = 1472 + sr0; if (k0c > 1499) k0c = 1499;
            int k1c = 1472 + sr1; if (k1c > 1499) k1c = 1499;
            gld16(kd0 + ((cur ^ 1) << 13), Kbh + ((long)k0c << 6) + sw0);
            gld16(kd1 + ((cur ^ 1) << 13), Kbh + ((long)k1c << 6) + sw1);
            int v0c = 1472 + sw0; if (v0c > 1496) v0c = 1496;
            int v1c = 1472 + sw1; if (v1c > 1496) v1c = 1496;
            gld16(vd0 + ((cur ^ 1) << 13), Vtb + (long)sr0 * 1504 + v0c);
            gld16(vd1 + ((cur ^ 1) << 13), Vtb + (long)sr1 * 1504 + v1c);
        }
        const unsigned char* Kl = lds + (cur << 13);
        const unsigned char* Vl = lds + 16384 + (cur << 13);

        // S^T = K Q^T for both sets: each ka fragment feeds 2 MFMAs
        f32x4 sA[4], sB[4];
        __builtin_amdgcn_s_setprio(1);
#pragma unroll
        for (int kt = 0; kt < 4; kt++) {
            const unsigned char* kp = Kl + ((kt * 16 + l15) << 7);
            bf16x8 ka0 = *(const bf16x8*)(kp + ((g ^ sk7) << 4));
            bf16x8 ka1 = *(const bf16x8*)(kp + (((g + 4) ^ sk7) << 4));
            f32x4 zA = fzero4(), zB = fzero4();
            zA = __builtin_amdgcn_mfma_f32_16x16x32_bf16(ka0, qb0A, zA, 0, 0, 0);
            zB = __builtin_amdgcn_mfma_f32_16x16x32_bf16(ka0, qb0B, zB, 0, 0, 0);
            zA = __builtin_amdgcn_mfma_f32_16x16x32_bf16(ka1, qb1A, zA, 0, 0, 0);
            zB = __builtin_amdgcn_mfma_f32_16x16x32_bf16(ka1, qb1B, zB, 0, 0, 0);
            sA[kt] = zA; sB[kt] = zB;
        }
        __builtin_amdgcn_s_setprio(0);
        if (tile == 23) {   // mask keys >= 1500 (kv0 = 1472, 28 valid) -- key-dependent only
#pragma unroll
            for (int kt = 0; kt < 4; kt++)
#pragma unroll
                for (int r = 0; r < 4; r++)
                    if (kt * 16 + g * 4 + r >= 28) { sA[kt][r] = -1e30f; sB[kt][r] = -1e30f; }
        }

        // P = exp2(s); shift-free. psum in-lane per set.
        float pvA[4][4], pvB[4][4];
        float psA = 0.f, psB = 0.f;
#pragma unroll
        for (int kt = 0; kt < 4; kt++) {
#pragma unroll
            for (int r = 0; r < 4; r++) {
                float a2 = exp2f(sA[kt][r]);
                float b2 = exp2f(sB[kt][r]);
                pvA[kt][r] = a2; pvB[kt][r] = b2;
                psA += a2; psB += b2;
            }
        }
        lA += psA; lB += psB;

        // PV A-frags per set: elem j of pa0 = P[key 16*(j>>2)+4g+(j&3)] (permuted V cols 8g+j)
        bf16x8 pa0A, pa1A, pa0B, pa1B;
#pragma unroll
        for (int j = 0; j < 8; j++) {
            pa0A[j] = (__bf16)pvA[j >> 2][j & 3];
            pa1A[j] = (__bf16)pvA[2 + (j >> 2)][j & 3];
            pa0B[j] = (__bf16)pvB[j >> 2][j & 3];
            pa1B[j] = (__bf16)pvB[2 + (j >> 2)][j & 3];
        }

        // O += P V : each vb fragment feeds 2 MFMAs (one per set)
        __builtin_amdgcn_s_setprio(1);
#pragma unroll
        for (int nf = 0; nf < 4; nf++) {
            const unsigned char* vp = Vl + ((nf * 16 + l15) << 7);
            bf16x8 vb0 = *(const bf16x8*)(vp + ((g ^ sk7) << 4));
            bf16x8 vb1 = *(const bf16x8*)(vp + (((4 + g) ^ sk7) << 4));
            o_acc[0][nf] = __builtin_amdgcn_mfma_f32_16x16x32_bf16(pa0A, vb0, o_acc[0][nf], 0, 0, 0);
            o_acc[1][nf] = __builtin_amdgcn_mfma_f32_16x16x32_bf16(pa0B, vb0, o_acc[1][nf], 0, 0, 0);
            o_acc[0][nf] = __builtin_amdgcn_mfma_f32_16x16x32_bf16(pa1A, vb1, o_acc[0][nf], 0, 0, 0);
            o_acc[1][nf] = __builtin_amdgcn_mfma_f32_16x16x32_bf16(pa1B, vb1, o_acc[1][nf], 0, 0, 0);
        }
        __builtin_amdgcn_s_setprio(0);
        __syncthreads();   // next-tile loads landed; everyone done with buf[cur]
    }

    // epilogue: total l across g-groups per set, normalize, write O[token][c]
    lA += __shfl_xor(lA, 16); lA += __shfl_xor(lA, 32);
    lB += __shfl_xor(lB, 16); lB += __shfl_xor(lB, 32);
    float invA = 1.f / lA, invB = 1.f / lB;   // per q = set_base + l15
#pragma unroll
    for (int s2 = 0; s2 < 2; s2++) {
        float inv = s2 ? invB : invA;
#pragma unroll
        for (int r = 0; r < 4; r++) {
            float invr = __shfl(inv, g * 4 + r);      // inv for o_acc row q = 4g+r of this set
            int q = qt * 128 + wv * 32 + s2 * 16 + g * 4 + r;
            if (q < 1500) {
                u16* dst = O + ((long)(b * 1500 + q) << 10) + (h << 6);
#pragma unroll
                for (int nf = 0; nf < 4; nf++)
                    dst[nf * 16 + l15] = f2bf(o_acc[s2][nf][r] * invr);
            }
        }
    }
}

// ---------------- launch ----------------
extern "C" void kernel_launch(void* const* d_in, const int* in_sizes, int n_in,
                              void* d_out, int out_size, void* d_ws, size_t ws_size,
                              hipStream_t stream) {
    const float* x  = (const float*)d_in[0];
    const float* Wq = (const float*)d_in[1];
    const float* bq = (const float*)d_in[2];
    const float* Wk = (const float*)d_in[3];
    const float* Wv = (const float*)d_in[4];
    const float* bv = (const float*)d_in[5];
    const float* Wo = (const float*)d_in[6];
    const float* bo = (const float*)d_in[7];
    float* out = (float*)d_out;

    // workspace layout (bytes):
    //   xb [6000][1024] bf16 : 12,288,000   (reused as O_ws after qkv consumes it)
    //   wb [4][2^20]    bf16 :  8,388,608   (wq|wk|wv|wo rows = output channels)
    //   Q  [4][16][1500][64] : 12,288,000   (pre-scaled by 0.125*log2e)
    //   K                    : 12,288,000
    //   Vt [4][1024][1504]   : 12,320,768   (key-permuted cols, cols 1500-1503 zeroed)
    const size_t NEED = 57573376;
    if (ws_size < NEED) return;   // visible failure if workspace too small

    unsigned char* ws = (unsigned char*)d_ws;
    u16* xb = (u16*)(ws);
    u16* wb = (u16*)(ws + 12288000);
    u16* Qw = (u16*)(ws + 20676608);
    u16* Kw = (u16*)(ws + 32964608);
    u16* Vt = (u16*)(ws + 45252608);

    prep_k<<<dim3(5633), dim3(256), 0, stream>>>(Wq, Wk, Wv, Wo, wb, x, xb, Vt);
    qkv_k<<<dim3(1136), dim3(256), 0, stream>>>(xb, wb, bq, bv, Qw, Kw, Vt);   // 752 QK + 384 V
    attn_k<<<dim3(768), dim3(256), 0, stream>>>(Qw, Kw, Vt, xb /* -> O_ws */);
    gemm_out_k<<<dim3(376), dim3(256), 0, stream>>>(xb, wb, bo, out);
}